// Round 4
// baseline (865.480 us; speedup 1.0000x reference)
//
#include <hip/hip_runtime.h>
#include <stdint.h>

#define N_ROWS 32768
#define K_CB   8192
#define D_DIM  512
#define TAU    0.07f
#define BM     128
#define NKT    256

typedef __attribute__((ext_vector_type(8))) short bf16x8;
typedef __attribute__((ext_vector_type(16))) float f32x16;

static __device__ __forceinline__ unsigned short f2bf(float f) {
    unsigned u = __builtin_bit_cast(unsigned, f);
    u += 0x7FFFu + ((u >> 16) & 1u);          // round-to-nearest-even
    return (unsigned short)(u >> 16);
}

static __device__ __forceinline__ void glds16(const unsigned short* g, unsigned short* l) {
    __builtin_amdgcn_global_load_lds(
        (const __attribute__((address_space(1))) unsigned int*)g,
        (__attribute__((address_space(3))) unsigned int*)l, 16, 0, 0);
}

// codebook fp32 [K][512] -> two pre-swizzled bf16 arrays of 16B chunks per 32-row tile:
//  rm_sw: chunk c = cbl*64 + (dc ^ (cbl&7))        holds C[tile cb=cbl][d = dc*8 .. +7]
//  t_sw : chunk c = (d*4 + cbc) ^ ((d>>1)&7)       holds C[tile cb=cbc*8+e][d], e=0..7
__global__ __launch_bounds__(512) void prep_codebook(const float* __restrict__ cb,
                                                     unsigned short* __restrict__ rm_sw,
                                                     unsigned short* __restrict__ t_sw) {
    __shared__ unsigned short tile[32 * 512];     // row-major [cbl][d]
    const int j = blockIdx.x, t = threadIdx.x;
    const float2* src = (const float2*)(cb + (size_t)j * (32 * D_DIM));
    unsigned* t32 = (unsigned*)tile;
    #pragma unroll
    for (int it = 0; it < 16; ++it) {
        int e2 = it * 512 + t;
        float2 v = src[e2];
        t32[e2] = (unsigned)f2bf(v.x) | ((unsigned)f2bf(v.y) << 16);
    }
    __syncthreads();
    uint4* rmd = (uint4*)rm_sw + (size_t)j * 2048;
    uint4* twd = (uint4*)t_sw + (size_t)j * 2048;
    #pragma unroll
    for (int it = 0; it < 4; ++it) {
        int L = it * 512 + t;
        int cbl = L >> 6, dc = L & 63;
        int c = cbl * 64 + (dc ^ (cbl & 7));
        rmd[c] = *(const uint4*)&tile[cbl * 512 + dc * 8];
    }
    #pragma unroll
    for (int it = 0; it < 4; ++it) {
        int M = it * 512 + t;
        int d = M >> 2, cbc = M & 3;
        int c = (d * 4 + cbc) ^ ((d >> 1) & 7);
        unsigned short tmp[8];
        #pragma unroll
        for (int e = 0; e < 8; ++e) tmp[e] = tile[(cbc * 8 + e) * 512 + d];
        twd[c] = *(const uint4*)tmp;
    }
}

// 12-wave producer/consumer: waves 0..3 = S-role (32 rows each), waves 4..11 = PV-role
// (group p>>1, d-half p&1). PV lags S by one tile; ONE barrier per iteration.
__global__ __launch_bounds__(768) void cbmap_main(const float* __restrict__ x,
                                                  const unsigned short* __restrict__ rm_sw,
                                                  const unsigned short* __restrict__ t_sw,
                                                  float* __restrict__ out) {
    __shared__ unsigned short s_rm[2][16384];     // 2 x 32 KB  cb-major swizzled tile
    __shared__ unsigned short s_t[2][16384];      // 2 x 32 KB  d-major swizzled tile
    __shared__ unsigned short s_px[2][4][1024];   // 2 x 4 x 2 KB  P exchange [row][cb^cswz]
    __shared__ float s_ds[BM];                    // softmax denominators

    const int tid  = threadIdx.x;
    const int w    = tid >> 6, lane = tid & 63;
    const int n    = lane & 31, h = lane >> 5;
    const int cswz = 8 * ((n >> 1) & 3);          // px bank swizzle (row = n)

    if (w < 4) {
        // ======================= S-ROLE =======================
        const int g = w;
        // preload rm[0] (async; lands during prologue)
        #pragma unroll
        for (int k = 0; k < 8; ++k) {
            int c = tid + k * 256;
            glds16(rm_sw + (size_t)c * 8, &s_rm[0][c * 8]);
        }
        // prologue: load raw x row, sumsq; scale folded into exp arg later
        const float* xr = x + ((size_t)(blockIdx.x * BM + g * 32 + n)) * D_DIM + h * 8;
        float ss = 0.f;
        bf16x8 xf[32];
        #pragma unroll
        for (int kc = 0; kc < 32; ++kc) {
            float4 a = *(const float4*)(xr + kc * 16);
            float4 b = *(const float4*)(xr + kc * 16 + 4);
            ss += a.x*a.x + a.y*a.y + a.z*a.z + a.w*a.w;
            ss += b.x*b.x + b.y*b.y + b.z*b.z + b.w*b.w;
            bf16x8 f;
            f[0] = (short)f2bf(a.x); f[1] = (short)f2bf(a.y);
            f[2] = (short)f2bf(a.z); f[3] = (short)f2bf(a.w);
            f[4] = (short)f2bf(b.x); f[5] = (short)f2bf(b.y);
            f[6] = (short)f2bf(b.z); f[7] = (short)f2bf(b.w);
            xf[kc] = f;
        }
        ss += __shfl_xor(ss, 32, 64);
        const float scale = 1.0f / (fmaxf(sqrtf(ss), 1e-12f) * TAU);
        const int sw7 = n & 7;                    // rm swizzle (cb = n)
        float dsum = 0.f;
        __syncthreads();                          // B0

        for (int j = 0; j < NKT; ++j) {
            if (j + 1 < NKT) {                    // stage rm[j+1] -> other buffer
                const unsigned short* src = rm_sw + (size_t)(j + 1) * 16384;
                unsigned short* dst = &s_rm[(j + 1) & 1][0];
                #pragma unroll
                for (int k = 0; k < 8; ++k) {
                    int c = tid + k * 256;
                    glds16(src + (size_t)c * 8, dst + c * 8);
                }
            }
            // S^T = C_tile · x^T  (A = cb-major tile, B = x-frags; D: col=x-row=n)
            const unsigned short* rb = &s_rm[j & 1][0];
            f32x16 sacc;
            #pragma unroll
            for (int i = 0; i < 16; ++i) sacc[i] = 0.f;
            #pragma unroll
            for (int kc = 0; kc < 32; ++kc) {
                int dc = 2 * kc + h;
                bf16x8 cf = *(const bf16x8*)&rb[(n * 64 + (dc ^ sw7)) * 8];
                sacc = __builtin_amdgcn_mfma_f32_32x32x16_bf16(cf, xf[kc], sacc, 0, 0, 0);
            }
            // P = exp(S*scale); pack + swizzled px write; accumulate denominator
            unsigned short* pxw = &s_px[j & 1][g][0];
            #pragma unroll
            for (int qi = 0; qi < 4; ++qi) {
                float p0 = __expf(sacc[4*qi+0] * scale);
                float p1 = __expf(sacc[4*qi+1] * scale);
                float p2 = __expf(sacc[4*qi+2] * scale);
                float p3 = __expf(sacc[4*qi+3] * scale);
                dsum += (p0 + p1) + (p2 + p3);
                uint2 v;
                v.x = (unsigned)f2bf(p0) | ((unsigned)f2bf(p1) << 16);
                v.y = (unsigned)f2bf(p2) | ((unsigned)f2bf(p3) << 16);
                int cbq = 8 * qi + 4 * h;         // this lane's cb quad base
                *(uint2*)&pxw[n * 32 + (cbq ^ cswz)] = v;
            }
            __syncthreads();                      // B(j+1)
        }
        float tot = dsum + __shfl_xor(dsum, 32, 64);
        if (h == 0) s_ds[g * 32 + n] = tot;
        __syncthreads();                          // B257 (matches PV's last loop barrier)
    } else {
        // ======================= PV-ROLE =======================
        const int p = w - 4, g = p >> 1, dh = p & 1;
        const int idx = tid - 256;                // 0..511
        f32x16 acc[8];
        #pragma unroll
        for (int i = 0; i < 8; ++i)
            #pragma unroll
            for (int r = 0; r < 16; ++r) acc[i][r] = 0.f;
        __syncthreads();                          // B0

        for (int j = 0; j <= NKT; ++j) {
            if (j < NKT) {                        // stage t[j] -> buffer j&1 (read at j+1)
                const unsigned short* src = t_sw + (size_t)j * 16384;
                unsigned short* dst = &s_t[j & 1][0];
                #pragma unroll
                for (int k = 0; k < 4; ++k) {
                    int c = idx + k * 512;
                    glds16(src + (size_t)c * 8, dst + c * 8);
                }
            }
            if (j > 0) {                          // consume tile j-1
                const int pb = (j + 1) & 1;       // == (j-1)&1
                const unsigned short* tb  = &s_t[pb][0];
                const unsigned short* pxb = &s_px[pb][g][0];
                bf16x8 a0 = *(const bf16x8*)&pxb[n * 32 + ((8 * h) ^ cswz)];        // cb 0..15
                bf16x8 a1 = *(const bf16x8*)&pxb[n * 32 + ((16 + 8 * h) ^ cswz)];   // cb 16..31
                #pragma unroll
                for (int nt = 0; nt < 8; ++nt) {
                    int d = dh * 256 + nt * 32 + n;
                    int dsw = (d >> 1) & 7;
                    bf16x8 b0 = *(const bf16x8*)&tb[(((d * 4) + h)     ^ dsw) * 8];
                    bf16x8 b1 = *(const bf16x8*)&tb[(((d * 4) + 2 + h) ^ dsw) * 8];
                    acc[nt] = __builtin_amdgcn_mfma_f32_32x32x16_bf16(a0, b0, acc[nt], 0, 0, 0);
                    acc[nt] = __builtin_amdgcn_mfma_f32_32x32x16_bf16(a1, b1, acc[nt], 0, 0, 0);
                }
            }
            __syncthreads();                      // B(j+1) .. B257
        }
        // epilogue: divide by denominator, store (s_ds ready after last barrier)
        float* ob = out + (size_t)(blockIdx.x * BM + g * 32) * D_DIM + dh * 256 + n;
        #pragma unroll
        for (int reg = 0; reg < 16; ++reg) {
            int rl = (reg & 3) + 8 * (reg >> 2) + 4 * h;
            float inv = 1.0f / s_ds[g * 32 + rl];
            #pragma unroll
            for (int nt = 0; nt < 8; ++nt) {
                ob[(size_t)rl * D_DIM + nt * 32] = acc[nt][reg] * inv;
            }
        }
    }
}

extern "C" void kernel_launch(void* const* d_in, const int* in_sizes, int n_in,
                              void* d_out, int out_size, void* d_ws, size_t ws_size,
                              hipStream_t stream) {
    const float* x  = (const float*)d_in[0];
    const float* cb = (const float*)d_in[1];
    unsigned short* rm_sw = (unsigned short*)d_ws;                       // 8 MB
    unsigned short* t_sw  = rm_sw + (size_t)K_CB * D_DIM;                // 8 MB
    float* outp = (float*)d_out;

    prep_codebook<<<NKT, 512, 0, stream>>>(cb, rm_sw, t_sw);
    cbmap_main<<<N_ROWS / BM, 768, 0, stream>>>(x, rm_sw, t_sw, outp);
}